// Round 3
// baseline (744.026 us; speedup 1.0000x reference)
//
#include <hip/hip_runtime.h>
#include <hip/hip_bf16.h>
#include <math.h>

// Problem constants (from reference)
#define B_ 8
#define T_ 1024
#define D_ 256
#define K_ 100
#define G_ 2
#define V_ 320
#define NT_ 101            // 1 positive + K negatives
#define TEMP_ 0.1f
#define DIV_W_ 0.1f
#define L2_W_ 10.0f
#define DIV_EPS_ 1e-7f
#define COS_EPS_ 1e-8f

// ws float layout (keep top below 17408 floats = known-good ws_size)
#define WS_LOSSC 0          // loss_c accumulator
#define WS_AVG   2          // 640 avg-prob accumulators
#define WS_DONE  642        // done-counter (int)
#define WS_FLAG  643        // mask-layout flag (int)
#define WS_SSQ   644        // 256 per-block ssq partials
#define WS_QNORM 900        // 8192
#define WS_CNORM 9092       // 8192   (top = 17284 floats = 69136 B)

#define K1_BLOCKS 256
#define CB_BLOCKS 256
#define CT_BLOCKS (B_ * T_)
#define TOTAL_BLOCKS (CB_BLOCKS + CT_BLOCKS)

// ---------------------------------------------------------------------------
// Kernel 1: per-row norms of quant/ctx, per-block ssq partials, mask-format
// detection, and zero-init of the accumulators kernel 2 atomically updates.
// ---------------------------------------------------------------------------
__global__ __launch_bounds__(256) void prep_kernel(
    const float* __restrict__ q, const float* __restrict__ c,
    const unsigned int* __restrict__ maskw, float* __restrict__ ws)
{
    __shared__ float ls[4];
    __shared__ int sA, sB;
    const int tid = threadIdx.x;
    const int lane = tid & 63;
    const int wavein = tid >> 6;
    const int wave = blockIdx.x * 4 + wavein;
    float ssq = 0.0f;

    for (int r = wave; r < B_ * T_; r += K1_BLOCKS * 4) {
        const float4 v = ((const float4*)(q + (size_t)r * D_))[lane];
        float s = v.x * v.x + v.y * v.y + v.z * v.z + v.w * v.w;
        ssq += s;
        const float4 w = ((const float4*)(c + (size_t)r * D_))[lane];
        float s2 = w.x * w.x + w.y * w.y + w.z * w.z + w.w * w.w;
#pragma unroll
        for (int sh = 32; sh >= 1; sh >>= 1) {
            s  += __shfl_xor(s, sh);
            s2 += __shfl_xor(s2, sh);
        }
        if (lane == 0) {
            ws[WS_QNORM + r] = sqrtf(s);
            ws[WS_CNORM + r] = sqrtf(s2);
        }
    }
#pragma unroll
    for (int sh = 32; sh >= 1; sh >>= 1) ssq += __shfl_xor(ssq, sh);
    if (lane == 0) ls[wavein] = ssq;
    __syncthreads();
    if (tid == 0)
        ws[WS_SSQ + blockIdx.x] = ls[0] + ls[1] + ls[2] + ls[3];

    if (blockIdx.x == 0) {
        // zero the accumulators kernel 2 uses
        for (int i = tid; i < G_ * V_; i += 256) ws[WS_AVG + i] = 0.0f;
        if (tid == 0) {
            ws[WS_LOSSC] = 0.0f;
            ((int*)ws)[WS_DONE] = 0;
            sA = 0; sB = 0;
        }
        __syncthreads();
        // detect mask materialization: int32 / float32 / byte-bool
        int a = 0, b = 0;
        for (int i = tid; i < (B_ * T_) / 4; i += 256) {
            const unsigned int w = maskw[i];
            a |= (w > 1u) ? 1 : 0;
            b |= (w != 0u && w != 0x3F800000u) ? 1 : 0;
        }
        if (a) atomicOr(&sA, 1);
        if (b) atomicOr(&sB, 1);
        __syncthreads();
        if (tid == 0)
            ((int*)ws)[WS_FLAG] = (!sA) ? 0 : ((!sB) ? 1 : 2);
    }
}

// ---------------------------------------------------------------------------
// Finalize (run by the last block of kernel 2): entropy/perplexity, combine.
// Accumulator reads via atomicAdd(p, 0) to bypass any stale L1.
// ---------------------------------------------------------------------------
__device__ void finalize(float* ws, float* out) {
    const int tid = threadIdx.x;
    if (tid < 64) {
        float ss = ws[WS_SSQ + tid] + ws[WS_SSQ + 64 + tid]
                 + ws[WS_SSQ + 128 + tid] + ws[WS_SSQ + 192 + tid];
        float e0 = 0.0f, e1 = 0.0f;
        const float inv = 1.0f / (float)(B_ * T_);
#pragma unroll
        for (int i = 0; i < 5; i++) {
            const float a0 = atomicAdd(&ws[WS_AVG + tid + 64 * i], 0.0f) * inv;
            const float a1 = atomicAdd(&ws[WS_AVG + V_ + tid + 64 * i], 0.0f) * inv;
            e0 -= a0 * __logf(a0 + DIV_EPS_);
            e1 -= a1 * __logf(a1 + DIV_EPS_);
        }
#pragma unroll
        for (int s = 32; s >= 1; s >>= 1) {
            ss += __shfl_xor(ss, s);
            e0 += __shfl_xor(e0, s);
            e1 += __shfl_xor(e1, s);
        }
        if (tid == 0) {
            const float loss_c = atomicAdd(&ws[WS_LOSSC], 0.0f);
            const float loss_d = ((float)V_ - __expf(e0)) + ((float)V_ - __expf(e1));
            const float loss_l2 = ss / (float)(B_ * T_ * D_);
            out[0] = loss_c + DIV_W_ * loss_d + L2_W_ * loss_l2;
        }
    }
}

// ---------------------------------------------------------------------------
// Kernel 2: codebook blocks [0, 256) + contrastive blocks [256, 8448).
// Contrastive mapping b = cblk & 7 pins each batch to one XCD (blockIdx % 8
// round-robin) so quant[b]+ctx[b] (2 MB) stay resident in that XCD's 4 MB L2.
// Last block to finish runs finalize (device-scope atomics + threadfence).
// ---------------------------------------------------------------------------
__global__ __launch_bounds__(256) void fused_kernel(
    const float* __restrict__ quant,
    const float* __restrict__ ctx,
    const float* __restrict__ cb,
    const int* __restrict__ negidx,
    const void* __restrict__ maskp,
    float* __restrict__ ws,
    float* __restrict__ out)
{
    __shared__ float sh[G_ * V_];
    __shared__ int s_last;
    const int tid = threadIdx.x;

    if (blockIdx.x < CB_BLOCKS) {
        // ---------------- codebook diversity path ----------------
        for (int i = tid; i < G_ * V_; i += 256) sh[i] = 0.0f;
        __syncthreads();
        const int lane = tid & 63;
        const int wave = tid >> 6;
        const int base = blockIdx.x * 4 + wave;   // 0..1023
        float r0[5] = {0, 0, 0, 0, 0};
        float r1[5] = {0, 0, 0, 0, 0};
        const bool odd = (base & 1);
#pragma unroll 1
        for (int i = 0; i < 16; i++) {
            const int r = base + 1024 * i;        // parity constant per wave
            const float* row = cb + (size_t)r * V_;
            float v[5];
#pragma unroll
            for (int j = 0; j < 5; j++)
                v[j] = __builtin_nontemporal_load(&row[lane + 64 * j]);
            float mx = fmaxf(fmaxf(fmaxf(v[0], v[1]), fmaxf(v[2], v[3])), v[4]);
#pragma unroll
            for (int s = 32; s >= 1; s >>= 1) mx = fmaxf(mx, __shfl_xor(mx, s));
            float e[5], sum = 0.0f;
#pragma unroll
            for (int j = 0; j < 5; j++) { e[j] = __expf(v[j] - mx); sum += e[j]; }
#pragma unroll
            for (int s = 32; s >= 1; s >>= 1) sum += __shfl_xor(sum, s);
            const float is = 1.0f / sum;
            if (odd) {
#pragma unroll
                for (int j = 0; j < 5; j++) r1[j] += e[j] * is;
            } else {
#pragma unroll
                for (int j = 0; j < 5; j++) r0[j] += e[j] * is;
            }
        }
#pragma unroll
        for (int j = 0; j < 5; j++) {
            atomicAdd(&sh[0 * V_ + lane + 64 * j], r0[j]);
            atomicAdd(&sh[1 * V_ + lane + 64 * j], r1[j]);
        }
        __syncthreads();
        for (int i = tid; i < G_ * V_; i += 256)
            atomicAdd(&ws[WS_AVG + i], sh[i]);
    } else {
        // ---------------- contrastive path ----------------
        const int cblk = blockIdx.x - CB_BLOCKS;
        const int b = cblk & 7;                  // batch -> XCD affinity
        const int t = cblk >> 3;
        const int bt = b * T_ + t;

        const int flag = ((const int*)ws)[WS_FLAG];
        bool m;
        if (flag == 2)      m = ((const unsigned char*)maskp)[bt] != 0;
        else if (flag == 1) m = ((const float*)maskp)[bt] != 0.0f;
        else                m = ((const int*)maskp)[bt] != 0;

        if (m) {   // block-uniform: barriers inside are safe
            const int lane16 = tid & 15;
            const int grp = tid >> 4;            // 0..15

            const float4* pred4 = (const float4*)(ctx + (size_t)bt * D_);
            const float4 p0 = pred4[lane16];
            const float4 p1 = pred4[lane16 + 16];
            const float4 p2 = pred4[lane16 + 32];
            const float4 p3 = pred4[lane16 + 48];
            const float pn = ws[WS_CNORM + bt];

            const float4* qb = (const float4*)(quant + (size_t)b * T_ * D_);
            const float* qn = ws + WS_QNORM + b * T_;
            const int* nrow = negidx + (size_t)bt * K_;

            for (int k = grp; k < NT_; k += 32) {
                const int k2 = k + 16;
                const bool has1 = (k2 < NT_);
                const int idx0 = (k == 0) ? t : __builtin_nontemporal_load(&nrow[k - 1]);
                const int idx1 = has1 ? __builtin_nontemporal_load(&nrow[k2 - 1]) : idx0;

                const float tn0 = qn[idx0];
                const float tn1 = qn[idx1];

                const float4* r0p = qb + (size_t)idx0 * (D_ / 4);
                const float4* r1p = qb + (size_t)idx1 * (D_ / 4);
                const float4 a0 = r0p[lane16];
                const float4 a1 = r0p[lane16 + 16];
                const float4 a2 = r0p[lane16 + 32];
                const float4 a3 = r0p[lane16 + 48];
                const float4 b0 = r1p[lane16];
                const float4 b1 = r1p[lane16 + 16];
                const float4 b2 = r1p[lane16 + 32];
                const float4 b3 = r1p[lane16 + 48];

                float dt0 = p0.x*a0.x + p0.y*a0.y + p0.z*a0.z + p0.w*a0.w
                          + p1.x*a1.x + p1.y*a1.y + p1.z*a1.z + p1.w*a1.w
                          + p2.x*a2.x + p2.y*a2.y + p2.z*a2.z + p2.w*a2.w
                          + p3.x*a3.x + p3.y*a3.y + p3.z*a3.z + p3.w*a3.w;
                float dt1 = p0.x*b0.x + p0.y*b0.y + p0.z*b0.z + p0.w*b0.w
                          + p1.x*b1.x + p1.y*b1.y + p1.z*b1.z + p1.w*b1.w
                          + p2.x*b2.x + p2.y*b2.y + p2.z*b2.z + p2.w*b2.w
                          + p3.x*b3.x + p3.y*b3.y + p3.z*b3.z + p3.w*b3.w;
#pragma unroll
                for (int s = 8; s >= 1; s >>= 1) {
                    dt0 += __shfl_xor(dt0, s);
                    dt1 += __shfl_xor(dt1, s);
                }
                if (lane16 == 0) {
                    const float c0 = dt0 / fmaxf(pn * tn0, COS_EPS_);
                    sh[k] = (k > 0 && idx0 == t) ? -1e30f : c0 * (1.0f / TEMP_);
                    if (has1) {
                        const float c1 = dt1 / fmaxf(pn * tn1, COS_EPS_);
                        sh[k2] = (idx1 == t) ? -1e30f : c1 * (1.0f / TEMP_);
                    }
                }
            }
            __syncthreads();

            if (tid < 64) {
                const float l0 = (tid < NT_) ? sh[tid] : -1e30f;
                const float l1 = (tid + 64 < NT_) ? sh[tid + 64] : -1e30f;
                float mx = fmaxf(l0, l1);
#pragma unroll
                for (int s = 32; s >= 1; s >>= 1) mx = fmaxf(mx, __shfl_xor(mx, s));
                float sum = __expf(l0 - mx) + __expf(l1 - mx);
#pragma unroll
                for (int s = 32; s >= 1; s >>= 1) sum += __shfl_xor(sum, s);
                if (tid == 0) {
                    const float logp0 = sh[0] - (mx + __logf(sum));
                    atomicAdd(&ws[WS_LOSSC], -logp0);
                }
            }
        }
    }

    // ---------------- common tail: done-count + last-block finalize ----------
    __threadfence();                       // release our global writes
    if (tid == 0) {
        const int old = atomicAdd((int*)ws + WS_DONE, 1);
        s_last = (old == TOTAL_BLOCKS - 1) ? 1 : 0;
    }
    __syncthreads();
    if (s_last) {
        __threadfence();                   // acquire others' writes
        finalize(ws, out);
    }
}

extern "C" void kernel_launch(void* const* d_in, const int* in_sizes, int n_in,
                              void* d_out, int out_size, void* d_ws, size_t ws_size,
                              hipStream_t stream) {
    const float* quant = (const float*)d_in[0];
    const float* ctx   = (const float*)d_in[1];
    const float* cb    = (const float*)d_in[2];
    const int*   nidx  = (const int*)d_in[3];
    const void*  mask  = d_in[4];
    float* ws  = (float*)d_ws;
    float* out = (float*)d_out;

    prep_kernel<<<K1_BLOCKS, 256, 0, stream>>>(quant, ctx,
                                               (const unsigned int*)mask, ws);
    fused_kernel<<<TOTAL_BLOCKS, 256, 0, stream>>>(quant, ctx, cb, nidx, mask,
                                                   ws, out);
}

// Round 4
// 174.388 us; speedup vs baseline: 4.2665x; 4.2665x over previous
//
#include <hip/hip_runtime.h>
#include <hip/hip_bf16.h>
#include <math.h>

// Problem constants (from reference)
#define B_ 8
#define T_ 1024
#define D_ 256
#define K_ 100
#define G_ 2
#define V_ 320
#define NT_ 101            // 1 positive + K negatives
#define TEMP_ 0.1f
#define DIV_W_ 0.1f
#define L2_W_ 10.0f
#define DIV_EPS_ 1e-7f
#define COS_EPS_ 1e-8f

// ws float layout (top = 17408 floats = 69632 B, known-good)
#define WS_LOSSC 0          // loss_c accumulator
#define WS_AVG   2          // 640 avg-prob accumulators
#define WS_FLAG  643        // mask-layout flag (int)
#define WS_SSQ   644        // 256 per-block ssq partials (norm blocks)
#define WS_QNORM 1024       // 8192
#define WS_CNORM 9216       // 8192

#define NORM_BLOCKS 256
#define CB_BLOCKS   256

// ---------------------------------------------------------------------------
// Prep: blocks [0,256) = batch-affine norms (+ssq partials, block 0 also
// detects the mask layout); blocks [256,512) = codebook softmax accumulation.
// Norms blocks use the same b = blk&7 mapping as the contrastive kernel, so
// each XCD's L2 is pre-warmed with exactly the quant/ctx batch it will gather
// from later. Codebook rows are nontemporal so the 21 MB stream doesn't evict
// the warmed data.
// ---------------------------------------------------------------------------
__global__ __launch_bounds__(256) void prep_kernel(
    const float* __restrict__ q, const float* __restrict__ c,
    const float* __restrict__ cb, const unsigned int* __restrict__ maskw,
    float* __restrict__ ws)
{
    __shared__ float sh[G_ * V_];
    __shared__ int sA, sB;
    const int tid = threadIdx.x;
    const int lane = tid & 63;
    const int wavein = tid >> 6;
    const int blk = blockIdx.x;

    if (blk < NORM_BLOCKS) {
        // ---------------- batch-affine norms + ssq ----------------
        const int b = blk & 7;             // XCD affinity (blockIdx % 8)
        const int seg = blk >> 3;          // 0..31 : rows seg*32 .. seg*32+31
        float ssq = 0.0f;
#pragma unroll 1
        for (int i = 0; i < 8; i++) {
            const int r = b * T_ + seg * 32 + wavein * 8 + i;
            const float4 v = ((const float4*)(q + (size_t)r * D_))[lane];
            float s = v.x * v.x + v.y * v.y + v.z * v.z + v.w * v.w;
            ssq += s;
            const float4 w = ((const float4*)(c + (size_t)r * D_))[lane];
            float s2 = w.x * w.x + w.y * w.y + w.z * w.z + w.w * w.w;
#pragma unroll
            for (int sft = 32; sft >= 1; sft >>= 1) {
                s  += __shfl_xor(s, sft);
                s2 += __shfl_xor(s2, sft);
            }
            if (lane == 0) {
                ws[WS_QNORM + r] = sqrtf(s);
                ws[WS_CNORM + r] = sqrtf(s2);
            }
        }
#pragma unroll
        for (int sft = 32; sft >= 1; sft >>= 1) ssq += __shfl_xor(ssq, sft);
        if (lane == 0) sh[wavein] = ssq;
        __syncthreads();
        if (tid == 0)
            ws[WS_SSQ + blk] = sh[0] + sh[1] + sh[2] + sh[3];

        if (blk == 0) {
            // detect mask materialization: int32 / float32 / byte-bool
            if (tid == 0) { sA = 0; sB = 0; }
            __syncthreads();
            int a = 0, bb = 0;
            for (int i = tid; i < (B_ * T_) / 4; i += 256) {
                const unsigned int w = maskw[i];
                a  |= (w > 1u) ? 1 : 0;
                bb |= (w != 0u && w != 0x3F800000u) ? 1 : 0;
            }
            if (a)  atomicOr(&sA, 1);
            if (bb) atomicOr(&sB, 1);
            __syncthreads();
            if (tid == 0)
                ((int*)ws)[WS_FLAG] = (!sA) ? 0 : ((!sB) ? 1 : 2);
        }
    } else {
        // ---------------- codebook diversity path ----------------
        for (int i = tid; i < G_ * V_; i += 256) sh[i] = 0.0f;
        __syncthreads();
        const int cblk = blk - NORM_BLOCKS;       // 0..255
        const int base = cblk * 4 + wavein;       // 0..1023
        float r0[5] = {0, 0, 0, 0, 0};
        float r1[5] = {0, 0, 0, 0, 0};
        const bool odd = (base & 1);
#pragma unroll 1
        for (int i = 0; i < 16; i++) {
            const int r = base + 1024 * i;        // parity constant per wave
            const float* row = cb + (size_t)r * V_;
            float v[5];
#pragma unroll
            for (int j = 0; j < 5; j++)
                v[j] = __builtin_nontemporal_load(&row[lane + 64 * j]);
            float mx = fmaxf(fmaxf(fmaxf(v[0], v[1]), fmaxf(v[2], v[3])), v[4]);
#pragma unroll
            for (int s = 32; s >= 1; s >>= 1) mx = fmaxf(mx, __shfl_xor(mx, s));
            float e[5], sum = 0.0f;
#pragma unroll
            for (int j = 0; j < 5; j++) { e[j] = __expf(v[j] - mx); sum += e[j]; }
#pragma unroll
            for (int s = 32; s >= 1; s >>= 1) sum += __shfl_xor(sum, s);
            const float is = 1.0f / sum;
            if (odd) {
#pragma unroll
                for (int j = 0; j < 5; j++) r1[j] += e[j] * is;
            } else {
#pragma unroll
                for (int j = 0; j < 5; j++) r0[j] += e[j] * is;
            }
        }
#pragma unroll
        for (int j = 0; j < 5; j++) {
            atomicAdd(&sh[0 * V_ + lane + 64 * j], r0[j]);
            atomicAdd(&sh[1 * V_ + lane + 64 * j], r1[j]);
        }
        __syncthreads();
        for (int i = tid; i < G_ * V_; i += 256)
            atomicAdd(&ws[WS_AVG + i], sh[i]);
    }
}

// ---------------------------------------------------------------------------
// Contrastive loss: one block per (b,t) with b = blk&7 XCD affinity so each
// XCD gathers only from its own 2 MB (quant[b]+ctx[b]) resident in L2.
// 16 lane-groups x 16 lanes; 2 targets per group-iteration for MLP.
// ---------------------------------------------------------------------------
__global__ __launch_bounds__(256) void contrastive_kernel(
    const float* __restrict__ quant,
    const float* __restrict__ ctx,
    const int* __restrict__ negidx,
    const void* __restrict__ maskp,
    float* __restrict__ ws)
{
    const int cblk = blockIdx.x;
    const int b = cblk & 7;                  // batch -> XCD affinity
    const int t = cblk >> 3;
    const int bt = b * T_ + t;

    const int flag = ((const int*)ws)[WS_FLAG];
    bool m;
    if (flag == 2)      m = ((const unsigned char*)maskp)[bt] != 0;
    else if (flag == 1) m = ((const float*)maskp)[bt] != 0.0f;
    else                m = ((const int*)maskp)[bt] != 0;
    if (!m) return;   // block-uniform

    __shared__ float sh[NT_ + 3];
    const int tid = threadIdx.x;
    const int lane16 = tid & 15;
    const int grp = tid >> 4;                // 0..15

    const float4* pred4 = (const float4*)(ctx + (size_t)bt * D_);
    const float4 p0 = pred4[lane16];
    const float4 p1 = pred4[lane16 + 16];
    const float4 p2 = pred4[lane16 + 32];
    const float4 p3 = pred4[lane16 + 48];
    const float pn = ws[WS_CNORM + bt];

    const float4* qb = (const float4*)(quant + (size_t)b * T_ * D_);
    const float* qn = ws + WS_QNORM + b * T_;
    const int* nrow = negidx + (size_t)bt * K_;

    for (int k = grp; k < NT_; k += 32) {
        const int k2 = k + 16;
        const bool has1 = (k2 < NT_);
        const int idx0 = (k == 0) ? t : nrow[k - 1];
        const int idx1 = has1 ? nrow[k2 - 1] : idx0;   // k2 >= 16, never pos

        const float tn0 = qn[idx0];
        const float tn1 = qn[idx1];

        const float4* r0p = qb + (size_t)idx0 * (D_ / 4);
        const float4* r1p = qb + (size_t)idx1 * (D_ / 4);
        const float4 a0 = r0p[lane16];
        const float4 a1 = r0p[lane16 + 16];
        const float4 a2 = r0p[lane16 + 32];
        const float4 a3 = r0p[lane16 + 48];
        const float4 b0 = r1p[lane16];
        const float4 b1 = r1p[lane16 + 16];
        const float4 b2 = r1p[lane16 + 32];
        const float4 b3 = r1p[lane16 + 48];

        float dt0 = p0.x*a0.x + p0.y*a0.y + p0.z*a0.z + p0.w*a0.w
                  + p1.x*a1.x + p1.y*a1.y + p1.z*a1.z + p1.w*a1.w
                  + p2.x*a2.x + p2.y*a2.y + p2.z*a2.z + p2.w*a2.w
                  + p3.x*a3.x + p3.y*a3.y + p3.z*a3.z + p3.w*a3.w;
        float dt1 = p0.x*b0.x + p0.y*b0.y + p0.z*b0.z + p0.w*b0.w
                  + p1.x*b1.x + p1.y*b1.y + p1.z*b1.z + p1.w*b1.w
                  + p2.x*b2.x + p2.y*b2.y + p2.z*b2.z + p2.w*b2.w
                  + p3.x*b3.x + p3.y*b3.y + p3.z*b3.z + p3.w*b3.w;
#pragma unroll
        for (int s = 8; s >= 1; s >>= 1) {
            dt0 += __shfl_xor(dt0, s);
            dt1 += __shfl_xor(dt1, s);
        }
        if (lane16 == 0) {
            const float c0 = dt0 / fmaxf(pn * tn0, COS_EPS_);
            sh[k] = (k > 0 && idx0 == t) ? -1e30f : c0 * (1.0f / TEMP_);
            if (has1) {
                const float c1 = dt1 / fmaxf(pn * tn1, COS_EPS_);
                sh[k2] = (idx1 == t) ? -1e30f : c1 * (1.0f / TEMP_);
            }
        }
    }
    __syncthreads();

    if (tid < 64) {
        const float l0 = (tid < NT_) ? sh[tid] : -1e30f;
        const float l1 = (tid + 64 < NT_) ? sh[tid + 64] : -1e30f;
        float mx = fmaxf(l0, l1);
#pragma unroll
        for (int s = 32; s >= 1; s >>= 1) mx = fmaxf(mx, __shfl_xor(mx, s));
        float sum = __expf(l0 - mx) + __expf(l1 - mx);
#pragma unroll
        for (int s = 32; s >= 1; s >>= 1) sum += __shfl_xor(sum, s);
        if (tid == 0) {
            const float logp0 = sh[0] - (mx + __logf(sum));
            atomicAdd(&ws[WS_LOSSC], -logp0);
        }
    }
}

// ---------------------------------------------------------------------------
// Finalize: entropy/perplexity per group, combine all three losses.
// ---------------------------------------------------------------------------
__global__ void finalize_kernel(const float* __restrict__ ws,
                                float* __restrict__ out)
{
    const int lane = threadIdx.x;   // 64 threads
    float ss = 0.0f;
#pragma unroll
    for (int i = 0; i < 4; i++) ss += ws[WS_SSQ + lane + 64 * i];
    const float* avg = ws + WS_AVG;
    float e0 = 0.0f, e1 = 0.0f;
    const float inv = 1.0f / (float)(B_ * T_);
#pragma unroll
    for (int i = 0; i < 5; i++) {
        const float a0 = avg[0 * V_ + lane + 64 * i] * inv;
        const float a1 = avg[1 * V_ + lane + 64 * i] * inv;
        e0 -= a0 * __logf(a0 + DIV_EPS_);
        e1 -= a1 * __logf(a1 + DIV_EPS_);
    }
#pragma unroll
    for (int s = 32; s >= 1; s >>= 1) {
        ss += __shfl_xor(ss, s);
        e0 += __shfl_xor(e0, s);
        e1 += __shfl_xor(e1, s);
    }
    if (lane == 0) {
        const float loss_d = ((float)V_ - __expf(e0)) + ((float)V_ - __expf(e1));
        const float loss_l2 = ss / (float)(B_ * T_ * D_);
        out[0] = ws[WS_LOSSC] + DIV_W_ * loss_d + L2_W_ * loss_l2;
    }
}

extern "C" void kernel_launch(void* const* d_in, const int* in_sizes, int n_in,
                              void* d_out, int out_size, void* d_ws, size_t ws_size,
                              hipStream_t stream) {
    const float* quant = (const float*)d_in[0];
    const float* ctx   = (const float*)d_in[1];
    const float* cb    = (const float*)d_in[2];
    const int*   nidx  = (const int*)d_in[3];
    const void*  mask  = d_in[4];
    float* ws  = (float*)d_ws;
    float* out = (float*)d_out;

    // zero loss_c + avg accumulators (+flag slot)
    hipMemsetAsync(d_ws, 0, (WS_SSQ) * sizeof(float), stream);

    prep_kernel<<<NORM_BLOCKS + CB_BLOCKS, 256, 0, stream>>>(
        quant, ctx, cb, (const unsigned int*)mask, ws);
    contrastive_kernel<<<B_ * T_, 256, 0, stream>>>(quant, ctx, nidx, mask, ws);
    finalize_kernel<<<1, 64, 0, stream>>>(ws, out);
}

// Round 5
// 172.504 us; speedup vs baseline: 4.3131x; 1.0109x over previous
//
#include <hip/hip_runtime.h>
#include <hip/hip_bf16.h>
#include <math.h>

// Problem constants (from reference)
#define B_ 8
#define T_ 1024
#define D_ 256
#define K_ 100
#define G_ 2
#define V_ 320
#define NT_ 101            // 1 positive + K negatives
#define TEMP_ 0.1f
#define DIV_W_ 0.1f
#define L2_W_ 10.0f
#define DIV_EPS_ 1e-7f
#define COS_EPS_ 1e-8f

// ws float layout (top = 17408 floats = 69632 B, known-good)
#define WS_LOSSC 0          // loss_c accumulator
#define WS_AVG   2          // 640 avg-prob accumulators
#define WS_FLAG  643        // mask-layout flag (int)
#define WS_SSQ   644        // 256 per-block ssq partials (norm blocks)
#define WS_QNORM 1024       // 8192
#define WS_CNORM 9216       // 8192

#define NORM_BLOCKS 256
#define CB_BLOCKS   256

// ---------------------------------------------------------------------------
// Prep: blocks [0,256) = batch-affine norms (+ssq partials, block 0 also
// detects the mask layout); blocks [256,512) = codebook softmax accumulation.
// Norm blocks use the same b = blk&7 mapping as the contrastive kernel so
// each XCD's L2 is pre-warmed with the exact quant/ctx batch it gathers later.
// ---------------------------------------------------------------------------
__global__ __launch_bounds__(256) void prep_kernel(
    const float* __restrict__ q, const float* __restrict__ c,
    const float* __restrict__ cb, const unsigned int* __restrict__ maskw,
    float* __restrict__ ws)
{
    __shared__ float sh[G_ * V_];
    __shared__ int sA, sB;
    const int tid = threadIdx.x;
    const int lane = tid & 63;
    const int wavein = tid >> 6;
    const int blk = blockIdx.x;

    if (blk < NORM_BLOCKS) {
        // ---------------- batch-affine norms + ssq ----------------
        const int b = blk & 7;             // XCD affinity (blockIdx % 8)
        const int seg = blk >> 3;          // 0..31
        float ssq = 0.0f;
#pragma unroll 1
        for (int i = 0; i < 8; i++) {
            const int r = b * T_ + seg * 32 + wavein * 8 + i;
            const float4 v = ((const float4*)(q + (size_t)r * D_))[lane];
            float s = v.x * v.x + v.y * v.y + v.z * v.z + v.w * v.w;
            ssq += s;
            const float4 w = ((const float4*)(c + (size_t)r * D_))[lane];
            float s2 = w.x * w.x + w.y * w.y + w.z * w.z + w.w * w.w;
#pragma unroll
            for (int sft = 32; sft >= 1; sft >>= 1) {
                s  += __shfl_xor(s, sft);
                s2 += __shfl_xor(s2, sft);
            }
            if (lane == 0) {
                ws[WS_QNORM + r] = sqrtf(s);
                ws[WS_CNORM + r] = sqrtf(s2);
            }
        }
#pragma unroll
        for (int sft = 32; sft >= 1; sft >>= 1) ssq += __shfl_xor(ssq, sft);
        if (lane == 0) sh[wavein] = ssq;
        __syncthreads();
        if (tid == 0)
            ws[WS_SSQ + blk] = sh[0] + sh[1] + sh[2] + sh[3];

        if (blk == 0) {
            if (tid == 0) { sA = 0; sB = 0; }
            __syncthreads();
            int a = 0, bb = 0;
            for (int i = tid; i < (B_ * T_) / 4; i += 256) {
                const unsigned int w = maskw[i];
                a  |= (w > 1u) ? 1 : 0;
                bb |= (w != 0u && w != 0x3F800000u) ? 1 : 0;
            }
            if (a)  atomicOr(&sA, 1);
            if (bb) atomicOr(&sB, 1);
            __syncthreads();
            if (tid == 0)
                ((int*)ws)[WS_FLAG] = (!sA) ? 0 : ((!sB) ? 1 : 2);
        }
    } else {
        // ---------------- codebook diversity path ----------------
        for (int i = tid; i < G_ * V_; i += 256) sh[i] = 0.0f;
        __syncthreads();
        const int cblk = blk - NORM_BLOCKS;       // 0..255
        const int base = cblk * 4 + wavein;       // 0..1023
        float r0[5] = {0, 0, 0, 0, 0};
        float r1[5] = {0, 0, 0, 0, 0};
        const bool odd = (base & 1);
#pragma unroll 1
        for (int i = 0; i < 16; i++) {
            const int r = base + 1024 * i;        // parity constant per wave
            const float* row = cb + (size_t)r * V_;
            float v[5];
#pragma unroll
            for (int j = 0; j < 5; j++)
                v[j] = __builtin_nontemporal_load(&row[lane + 64 * j]);
            float mx = fmaxf(fmaxf(fmaxf(v[0], v[1]), fmaxf(v[2], v[3])), v[4]);
#pragma unroll
            for (int s = 32; s >= 1; s >>= 1) mx = fmaxf(mx, __shfl_xor(mx, s));
            float e[5], sum = 0.0f;
#pragma unroll
            for (int j = 0; j < 5; j++) { e[j] = __expf(v[j] - mx); sum += e[j]; }
#pragma unroll
            for (int s = 32; s >= 1; s >>= 1) sum += __shfl_xor(sum, s);
            const float is = 1.0f / sum;
            if (odd) {
#pragma unroll
                for (int j = 0; j < 5; j++) r1[j] += e[j] * is;
            } else {
#pragma unroll
                for (int j = 0; j < 5; j++) r0[j] += e[j] * is;
            }
        }
#pragma unroll
        for (int j = 0; j < 5; j++) {
            atomicAdd(&sh[0 * V_ + lane + 64 * j], r0[j]);
            atomicAdd(&sh[1 * V_ + lane + 64 * j], r1[j]);
        }
        __syncthreads();
        for (int i = tid; i < G_ * V_; i += 256)
            atomicAdd(&ws[WS_AVG + i], sh[i]);
    }
}

// ---------------------------------------------------------------------------
// Contrastive: one block per (b,t), b = blk&7 XCD affinity.
// Phase 1: indices + collision-flagged norms into LDS (breaks idx->gather
// dependence). Phase 2: 64 groups of 4 lanes; each group does <=2 targets;
// full row preloaded as 16 independent float4 loads (max MLP); pred slices
// broadcast from LDS; dot reduced with 2 quad_perm-class shuffles.
// ---------------------------------------------------------------------------
__global__ __launch_bounds__(256) void contrastive_kernel(
    const float* __restrict__ quant,
    const float* __restrict__ ctx,
    const int* __restrict__ negidx,
    const void* __restrict__ maskp,
    float* __restrict__ ws)
{
    const int cblk = blockIdx.x;
    const int b = cblk & 7;                  // batch -> XCD affinity
    const int t = cblk >> 3;
    const int bt = b * T_ + t;

    const int flag = ((const int*)ws)[WS_FLAG];
    bool m;
    if (flag == 2)      m = ((const unsigned char*)maskp)[bt] != 0;
    else if (flag == 1) m = ((const float*)maskp)[bt] != 0.0f;
    else                m = ((const int*)maskp)[bt] != 0;
    if (!m) return;   // block-uniform

    __shared__ float s_pred[D_];             // 1 KB
    __shared__ int   s_idx[NT_ + 3];
    __shared__ float s_tn[NT_ + 3];          // tn, or -1 for collision
    __shared__ float s_logit[NT_ + 3];

    const int tid = threadIdx.x;

    // phase 1a: pred row + raw indices
    if (tid < 64)
        ((float4*)s_pred)[tid] = ((const float4*)(ctx + (size_t)bt * D_))[tid];
    if (tid < K_)
        s_idx[tid + 1] = negidx[(size_t)bt * K_ + tid];
    if (tid == K_)
        s_idx[0] = t;
    __syncthreads();
    // phase 1b: norms (gathered once, collision folded in)
    if (tid < NT_) {
        const int idx = s_idx[tid];
        const bool col = (tid > 0) && (idx == t);
        s_tn[tid] = col ? -1.0f : ws[WS_QNORM + b * T_ + idx];
    }
    __syncthreads();

    const float pn = ws[WS_CNORM + bt];
    const float* qbase = quant + (size_t)b * T_ * D_;
    const int g = tid >> 2;                  // 0..63
    const int p = tid & 3;

#pragma unroll
    for (int pass = 0; pass < 2; ++pass) {
        const int k = g + 64 * pass;
        if (k < NT_) {
            const int idx = s_idx[k];
            const float4* row = (const float4*)(qbase + (size_t)idx * D_);
            // preload whole row slice: 16 independent float4 loads
            float4 r[16];
#pragma unroll
            for (int i = 0; i < 16; ++i) r[i] = row[i * 4 + p];
            float dot = 0.0f;
#pragma unroll
            for (int i = 0; i < 16; ++i) {
                const float4 q = ((const float4*)s_pred)[i * 4 + p];
                dot += r[i].x * q.x + r[i].y * q.y
                     + r[i].z * q.z + r[i].w * q.w;
            }
            // 4-lane reduce: masks 1,2 -> quad-perm class (fast DPP)
            dot += __shfl_xor(dot, 1);
            dot += __shfl_xor(dot, 2);
            if (p == 0) {
                const float tn = s_tn[k];
                s_logit[k] = (tn < 0.0f) ? -1e30f
                    : (dot / fmaxf(pn * tn, COS_EPS_)) * (1.0f / TEMP_);
            }
        }
    }
    __syncthreads();

    // softmax over s_logit[0..100] -> -logp0, one atomic per block
    if (tid < 64) {
        const float l0 = s_logit[tid];
        const float l1 = (tid + 64 < NT_) ? s_logit[tid + 64] : -1e30f;
        float mx = fmaxf(l0, l1);
#pragma unroll
        for (int s = 32; s >= 1; s >>= 1) mx = fmaxf(mx, __shfl_xor(mx, s));
        float sum = __expf(l0 - mx) + __expf(l1 - mx);
#pragma unroll
        for (int s = 32; s >= 1; s >>= 1) sum += __shfl_xor(sum, s);
        if (tid == 0) {
            const float logp0 = s_logit[0] - (mx + __logf(sum));
            atomicAdd(&ws[WS_LOSSC], -logp0);
        }
    }
}

// ---------------------------------------------------------------------------
// Finalize: entropy/perplexity per group, combine all three losses.
// ---------------------------------------------------------------------------
__global__ void finalize_kernel(const float* __restrict__ ws,
                                float* __restrict__ out)
{
    const int lane = threadIdx.x;   // 64 threads
    float ss = 0.0f;
#pragma unroll
    for (int i = 0; i < 4; i++) ss += ws[WS_SSQ + lane + 64 * i];
    const float* avg = ws + WS_AVG;
    float e0 = 0.0f, e1 = 0.0f;
    const float inv = 1.0f / (float)(B_ * T_);
#pragma unroll
    for (int i = 0; i < 5; i++) {
        const float a0 = avg[0 * V_ + lane + 64 * i] * inv;
        const float a1 = avg[1 * V_ + lane + 64 * i] * inv;
        e0 -= a0 * __logf(a0 + DIV_EPS_);
        e1 -= a1 * __logf(a1 + DIV_EPS_);
    }
#pragma unroll
    for (int s = 32; s >= 1; s >>= 1) {
        ss += __shfl_xor(ss, s);
        e0 += __shfl_xor(e0, s);
        e1 += __shfl_xor(e1, s);
    }
    if (lane == 0) {
        const float loss_d = ((float)V_ - __expf(e0)) + ((float)V_ - __expf(e1));
        const float loss_l2 = ss / (float)(B_ * T_ * D_);
        out[0] = ws[WS_LOSSC] + DIV_W_ * loss_d + L2_W_ * loss_l2;
    }
}

extern "C" void kernel_launch(void* const* d_in, const int* in_sizes, int n_in,
                              void* d_out, int out_size, void* d_ws, size_t ws_size,
                              hipStream_t stream) {
    const float* quant = (const float*)d_in[0];
    const float* ctx   = (const float*)d_in[1];
    const float* cb    = (const float*)d_in[2];
    const int*   nidx  = (const int*)d_in[3];
    const void*  mask  = d_in[4];
    float* ws  = (float*)d_ws;
    float* out = (float*)d_out;

    // zero loss_c + avg accumulators (+flag slot)
    hipMemsetAsync(d_ws, 0, (WS_SSQ) * sizeof(float), stream);

    prep_kernel<<<NORM_BLOCKS + CB_BLOCKS, 256, 0, stream>>>(
        quant, ctx, cb, (const unsigned int*)mask, ws);
    contrastive_kernel<<<B_ * T_, 256, 0, stream>>>(quant, ctx, nidx, mask, ws);
    finalize_kernel<<<1, 64, 0, stream>>>(ws, out);
}

// Round 6
// 170.023 us; speedup vs baseline: 4.3760x; 1.0146x over previous
//
#include <hip/hip_runtime.h>
#include <hip/hip_bf16.h>
#include <math.h>

// Problem constants (from reference)
#define B_ 8
#define T_ 1024
#define D_ 256
#define K_ 100
#define G_ 2
#define V_ 320
#define NT_ 101            // 1 positive + K negatives
#define TEMP_ 0.1f
#define DIV_W_ 0.1f
#define L2_W_ 10.0f
#define DIV_EPS_ 1e-7f
#define COS_EPS_ 1e-8f

// ws float layout
#define WS_LOSSC 0          // loss_c accumulator
#define WS_AVG   2          // 640 avg-prob accumulators
#define WS_FLAG  643        // mask-layout flag (int)
#define WS_SSQ   644        // 256 per-block ssq partials (norm blocks)
#define WS_QNORM 1024       // 8192
#define WS_CNORM 9216       // 8192
#define WS_QBF16 17408      // bf16 copy of quant: 8192 rows x 512 B = 4 MB
#define WS_BF16_BYTES ((size_t)(WS_QBF16 + (size_t)B_ * T_ * D_ / 2) * 4)

#define NORM_BLOCKS 256
#define CB_BLOCKS   256

__device__ inline unsigned short f2bf_rne(float f) {
    unsigned int u = __float_as_uint(f);
    u += 0x7FFFu + ((u >> 16) & 1u);
    return (unsigned short)(u >> 16);
}

// ---------------------------------------------------------------------------
// Prep: blocks [0,256) = batch-affine norms + ssq (+ optional bf16 pack of
// quant into ws; block 0 detects mask layout); blocks [256,512) = codebook
// softmax accumulation (nontemporal). Norm blocks use the same b = blk&7
// XCD mapping as contrastive, pre-warming each XCD's L2 with its batch.
// ---------------------------------------------------------------------------
template <bool PACK_BF16>
__global__ __launch_bounds__(256) void prep_kernel(
    const float* __restrict__ q, const float* __restrict__ c,
    const float* __restrict__ cb, const unsigned int* __restrict__ maskw,
    float* __restrict__ ws)
{
    __shared__ float sh[G_ * V_];
    __shared__ int sA, sB;
    const int tid = threadIdx.x;
    const int lane = tid & 63;
    const int wavein = tid >> 6;
    const int blk = blockIdx.x;

    if (blk < NORM_BLOCKS) {
        const int b = blk & 7;             // XCD affinity (blockIdx % 8)
        const int seg = blk >> 3;          // 0..31
        float ssq = 0.0f;
#pragma unroll 1
        for (int i = 0; i < 8; i++) {
            const int r = b * T_ + seg * 32 + wavein * 8 + i;
            const float4 v = ((const float4*)(q + (size_t)r * D_))[lane];
            float s = v.x * v.x + v.y * v.y + v.z * v.z + v.w * v.w;
            ssq += s;
            if (PACK_BF16) {
                ushort4 pk;
                pk.x = f2bf_rne(v.x); pk.y = f2bf_rne(v.y);
                pk.z = f2bf_rne(v.z); pk.w = f2bf_rne(v.w);
                ((ushort4*)((char*)ws + (size_t)WS_QBF16 * 4 +
                            (size_t)r * 512))[lane] = pk;
            }
            const float4 w = ((const float4*)(c + (size_t)r * D_))[lane];
            float s2 = w.x * w.x + w.y * w.y + w.z * w.z + w.w * w.w;
#pragma unroll
            for (int sft = 32; sft >= 1; sft >>= 1) {
                s  += __shfl_xor(s, sft);
                s2 += __shfl_xor(s2, sft);
            }
            if (lane == 0) {
                ws[WS_QNORM + r] = sqrtf(s);
                ws[WS_CNORM + r] = sqrtf(s2);
            }
        }
#pragma unroll
        for (int sft = 32; sft >= 1; sft >>= 1) ssq += __shfl_xor(ssq, sft);
        if (lane == 0) sh[wavein] = ssq;
        __syncthreads();
        if (tid == 0)
            ws[WS_SSQ + blk] = sh[0] + sh[1] + sh[2] + sh[3];

        if (blk == 0) {
            if (tid == 0) { sA = 0; sB = 0; }
            __syncthreads();
            int a = 0, bb = 0;
            for (int i = tid; i < (B_ * T_) / 4; i += 256) {
                const unsigned int w = maskw[i];
                a  |= (w > 1u) ? 1 : 0;
                bb |= (w != 0u && w != 0x3F800000u) ? 1 : 0;
            }
            if (a)  atomicOr(&sA, 1);
            if (bb) atomicOr(&sB, 1);
            __syncthreads();
            if (tid == 0)
                ((int*)ws)[WS_FLAG] = (!sA) ? 0 : ((!sB) ? 1 : 2);
        }
    } else {
        // ---------------- codebook diversity path ----------------
        for (int i = tid; i < G_ * V_; i += 256) sh[i] = 0.0f;
        __syncthreads();
        const int cblk = blk - NORM_BLOCKS;       // 0..255
        const int base = cblk * 4 + wavein;       // 0..1023
        float r0[5] = {0, 0, 0, 0, 0};
        float r1[5] = {0, 0, 0, 0, 0};
        const bool odd = (base & 1);
#pragma unroll 1
        for (int i = 0; i < 16; i++) {
            const int r = base + 1024 * i;        // parity constant per wave
            const float* row = cb + (size_t)r * V_;
            float v[5];
#pragma unroll
            for (int j = 0; j < 5; j++)
                v[j] = __builtin_nontemporal_load(&row[lane + 64 * j]);
            float mx = fmaxf(fmaxf(fmaxf(v[0], v[1]), fmaxf(v[2], v[3])), v[4]);
#pragma unroll
            for (int s = 32; s >= 1; s >>= 1) mx = fmaxf(mx, __shfl_xor(mx, s));
            float e[5], sum = 0.0f;
#pragma unroll
            for (int j = 0; j < 5; j++) { e[j] = __expf(v[j] - mx); sum += e[j]; }
#pragma unroll
            for (int s = 32; s >= 1; s >>= 1) sum += __shfl_xor(sum, s);
            const float is = 1.0f / sum;
            if (odd) {
#pragma unroll
                for (int j = 0; j < 5; j++) r1[j] += e[j] * is;
            } else {
#pragma unroll
                for (int j = 0; j < 5; j++) r0[j] += e[j] * is;
            }
        }
#pragma unroll
        for (int j = 0; j < 5; j++) {
            atomicAdd(&sh[0 * V_ + lane + 64 * j], r0[j]);
            atomicAdd(&sh[1 * V_ + lane + 64 * j], r1[j]);
        }
        __syncthreads();
        for (int i = tid; i < G_ * V_; i += 256)
            atomicAdd(&ws[WS_AVG + i], sh[i]);
    }
}

// ---------------------------------------------------------------------------
// Contrastive: one block per (b,t), b = blk&7 XCD affinity. Indices + norms
// prefetched to LDS; 64 groups of 4 lanes, <=2 targets each. BF16 path
// gathers 512 B rows from the ws copy (halves L1-miss-path bytes) and
// unpacks with pred kept fp32; FP32 path is the R5 fallback.
// ---------------------------------------------------------------------------
template <bool USE_BF16>
__global__ __launch_bounds__(256) void contrastive_kernel(
    const float* __restrict__ quant,
    const float* __restrict__ ctx,
    const int* __restrict__ negidx,
    const void* __restrict__ maskp,
    float* __restrict__ ws)
{
    const int cblk = blockIdx.x;
    const int b = cblk & 7;                  // batch -> XCD affinity
    const int t = cblk >> 3;
    const int bt = b * T_ + t;

    const int flag = ((const int*)ws)[WS_FLAG];
    bool m;
    if (flag == 2)      m = ((const unsigned char*)maskp)[bt] != 0;
    else if (flag == 1) m = ((const float*)maskp)[bt] != 0.0f;
    else                m = ((const int*)maskp)[bt] != 0;
    if (!m) return;   // block-uniform

    __shared__ float s_pred[D_];             // 1 KB
    __shared__ int   s_idx[NT_ + 3];
    __shared__ float s_tn[NT_ + 3];          // tn, or -1 for collision
    __shared__ float s_logit[NT_ + 3];

    const int tid = threadIdx.x;

    if (tid < 64)
        ((float4*)s_pred)[tid] = ((const float4*)(ctx + (size_t)bt * D_))[tid];
    if (tid < K_)
        s_idx[tid + 1] = negidx[(size_t)bt * K_ + tid];
    if (tid == K_)
        s_idx[0] = t;
    __syncthreads();
    if (tid < NT_) {
        const int idx = s_idx[tid];
        const bool col = (tid > 0) && (idx == t);
        s_tn[tid] = col ? -1.0f : ws[WS_QNORM + b * T_ + idx];
    }
    __syncthreads();

    const float pn = ws[WS_CNORM + bt];
    const int g = tid >> 2;                  // 0..63
    const int p = tid & 3;

#pragma unroll
    for (int pass = 0; pass < 2; ++pass) {
        const int k = g + 64 * pass;
        if (k < NT_) {
            const int idx = s_idx[k];
            float dot = 0.0f;
            if (USE_BF16) {
                const uint4* row = (const uint4*)((const char*)ws +
                    (size_t)WS_QBF16 * 4 + (size_t)(b * T_ + idx) * 512);
                uint4 u[8];
#pragma unroll
                for (int i = 0; i < 8; ++i) u[i] = row[i * 4 + p];
#pragma unroll
                for (int i = 0; i < 8; ++i) {
                    const int J0 = (p + 4 * i) * 4;   // uint index in row
                    const unsigned int w0 = u[i].x, w1 = u[i].y,
                                       w2 = u[i].z, w3 = u[i].w;
                    const float2 q0 = ((const float2*)s_pred)[J0 + 0];
                    const float2 q1 = ((const float2*)s_pred)[J0 + 1];
                    const float2 q2 = ((const float2*)s_pred)[J0 + 2];
                    const float2 q3 = ((const float2*)s_pred)[J0 + 3];
                    dot += __uint_as_float(w0 << 16) * q0.x
                         + __uint_as_float(w0 & 0xFFFF0000u) * q0.y
                         + __uint_as_float(w1 << 16) * q1.x
                         + __uint_as_float(w1 & 0xFFFF0000u) * q1.y
                         + __uint_as_float(w2 << 16) * q2.x
                         + __uint_as_float(w2 & 0xFFFF0000u) * q2.y
                         + __uint_as_float(w3 << 16) * q3.x
                         + __uint_as_float(w3 & 0xFFFF0000u) * q3.y;
                }
            } else {
                const float4* row = (const float4*)(quant +
                    ((size_t)b * T_ + idx) * D_);
                float4 r[16];
#pragma unroll
                for (int i = 0; i < 16; ++i) r[i] = row[i * 4 + p];
#pragma unroll
                for (int i = 0; i < 16; ++i) {
                    const float4 q = ((const float4*)s_pred)[i * 4 + p];
                    dot += r[i].x * q.x + r[i].y * q.y
                         + r[i].z * q.z + r[i].w * q.w;
                }
            }
            dot += __shfl_xor(dot, 1);
            dot += __shfl_xor(dot, 2);
            if (p == 0) {
                const float tn = s_tn[k];
                s_logit[k] = (tn < 0.0f) ? -1e30f
                    : (dot / fmaxf(pn * tn, COS_EPS_)) * (1.0f / TEMP_);
            }
        }
    }
    __syncthreads();

    if (tid < 64) {
        const float l0 = s_logit[tid];
        const float l1 = (tid + 64 < NT_) ? s_logit[tid + 64] : -1e30f;
        float mx = fmaxf(l0, l1);
#pragma unroll
        for (int s = 32; s >= 1; s >>= 1) mx = fmaxf(mx, __shfl_xor(mx, s));
        float sum = __expf(l0 - mx) + __expf(l1 - mx);
#pragma unroll
        for (int s = 32; s >= 1; s >>= 1) sum += __shfl_xor(sum, s);
        if (tid == 0) {
            const float logp0 = s_logit[0] - (mx + __logf(sum));
            atomicAdd(&ws[WS_LOSSC], -logp0);
        }
    }
}

// ---------------------------------------------------------------------------
// Finalize: entropy/perplexity per group, combine all three losses.
// ---------------------------------------------------------------------------
__global__ void finalize_kernel(const float* __restrict__ ws,
                                float* __restrict__ out)
{
    const int lane = threadIdx.x;   // 64 threads
    float ss = 0.0f;
#pragma unroll
    for (int i = 0; i < 4; i++) ss += ws[WS_SSQ + lane + 64 * i];
    const float* avg = ws + WS_AVG;
    float e0 = 0.0f, e1 = 0.0f;
    const float inv = 1.0f / (float)(B_ * T_);
#pragma unroll
    for (int i = 0; i < 5; i++) {
        const float a0 = avg[0 * V_ + lane + 64 * i] * inv;
        const float a1 = avg[1 * V_ + lane + 64 * i] * inv;
        e0 -= a0 * __logf(a0 + DIV_EPS_);
        e1 -= a1 * __logf(a1 + DIV_EPS_);
    }
#pragma unroll
    for (int s = 32; s >= 1; s >>= 1) {
        ss += __shfl_xor(ss, s);
        e0 += __shfl_xor(e0, s);
        e1 += __shfl_xor(e1, s);
    }
    if (lane == 0) {
        const float loss_d = ((float)V_ - __expf(e0)) + ((float)V_ - __expf(e1));
        const float loss_l2 = ss / (float)(B_ * T_ * D_);
        out[0] = ws[WS_LOSSC] + DIV_W_ * loss_d + L2_W_ * loss_l2;
    }
}

extern "C" void kernel_launch(void* const* d_in, const int* in_sizes, int n_in,
                              void* d_out, int out_size, void* d_ws, size_t ws_size,
                              hipStream_t stream) {
    const float* quant = (const float*)d_in[0];
    const float* ctx   = (const float*)d_in[1];
    const float* cb    = (const float*)d_in[2];
    const int*   nidx  = (const int*)d_in[3];
    const void*  mask  = d_in[4];
    float* ws  = (float*)d_ws;
    float* out = (float*)d_out;

    const bool bf16 = (ws_size >= WS_BF16_BYTES);

    // zero loss_c + avg accumulators (+flag slot)
    hipMemsetAsync(d_ws, 0, (WS_SSQ) * sizeof(float), stream);

    if (bf16) {
        prep_kernel<true><<<NORM_BLOCKS + CB_BLOCKS, 256, 0, stream>>>(
            quant, ctx, cb, (const unsigned int*)mask, ws);
        contrastive_kernel<true><<<B_ * T_, 256, 0, stream>>>(
            quant, ctx, nidx, mask, ws);
    } else {
        prep_kernel<false><<<NORM_BLOCKS + CB_BLOCKS, 256, 0, stream>>>(
            quant, ctx, cb, (const unsigned int*)mask, ws);
        contrastive_kernel<false><<<B_ * T_, 256, 0, stream>>>(
            quant, ctx, nidx, mask, ws);
    }
    finalize_kernel<<<1, 64, 0, stream>>>(ws, out);
}

// Round 9
// 134.599 us; speedup vs baseline: 5.5277x; 1.2632x over previous
//
#include <hip/hip_runtime.h>
#include <hip/hip_bf16.h>
#include <math.h>

// Problem constants (from reference)
#define B_ 8
#define T_ 1024
#define D_ 256
#define K_ 100
#define G_ 2
#define V_ 320
#define NT_ 101            // 1 positive + K negatives
#define TEMP_ 0.1f
#define DIV_W_ 0.1f
#define L2_W_ 10.0f
#define DIV_EPS_ 1e-7f
#define COS_EPS_ 1e-8f

// ws float layout
#define WS_LOSSC 0          // (legacy, still zeroed)
#define WS_AVG   2          // 640 avg-prob accumulators
#define WS_FLAG  643        // mask-layout flag (int)
#define WS_SSQ   644        // 256 per-block ssq partials (norm blocks)
#define WS_QNORM 1024       // 8192
#define WS_CNORM 9216       // 8192
#define WS_LOSSP 17408      // 8192 per-block loss partials (no atomics!)
#define WS_QBF16 25600      // bf16 copy of quant: 8192 rows x 512 B = 4 MB
#define WS_BF16_BYTES ((size_t)(WS_QBF16 + (size_t)B_ * T_ * D_ / 2) * 4)

#define NORM_BLOCKS 256
#define CB_BLOCKS   256

__device__ inline unsigned short f2bf_rne(float f) {
    unsigned int u = __float_as_uint(f);
    u += 0x7FFFu + ((u >> 16) & 1u);
    return (unsigned short)(u >> 16);
}

// ---------------------------------------------------------------------------
// Prep: blocks [0,256) = batch-affine norms + ssq (+ optional bf16 pack of
// quant into ws; block 0 detects mask layout); blocks [256,512) = codebook
// softmax accumulation (nontemporal). Norm blocks use the same b = blk&7
// XCD mapping as contrastive, pre-warming each XCD's L2 with its batch.
// ---------------------------------------------------------------------------
template <bool PACK_BF16>
__global__ __launch_bounds__(256) void prep_kernel(
    const float* __restrict__ q, const float* __restrict__ c,
    const float* __restrict__ cb, const unsigned int* __restrict__ maskw,
    float* __restrict__ ws)
{
    __shared__ float sh[G_ * V_];
    __shared__ int sA, sB;
    const int tid = threadIdx.x;
    const int lane = tid & 63;
    const int wavein = tid >> 6;
    const int blk = blockIdx.x;

    if (blk < NORM_BLOCKS) {
        const int b = blk & 7;             // XCD affinity (blockIdx % 8)
        const int seg = blk >> 3;          // 0..31
        float ssq = 0.0f;
#pragma unroll 1
        for (int i = 0; i < 8; i++) {
            const int r = b * T_ + seg * 32 + wavein * 8 + i;
            const float4 v = ((const float4*)(q + (size_t)r * D_))[lane];
            float s = v.x * v.x + v.y * v.y + v.z * v.z + v.w * v.w;
            ssq += s;
            if (PACK_BF16) {
                ushort4 pk;
                pk.x = f2bf_rne(v.x); pk.y = f2bf_rne(v.y);
                pk.z = f2bf_rne(v.z); pk.w = f2bf_rne(v.w);
                ((ushort4*)((char*)ws + (size_t)WS_QBF16 * 4 +
                            (size_t)r * 512))[lane] = pk;
            }
            const float4 w = ((const float4*)(c + (size_t)r * D_))[lane];
            float s2 = w.x * w.x + w.y * w.y + w.z * w.z + w.w * w.w;
#pragma unroll
            for (int sft = 32; sft >= 1; sft >>= 1) {
                s  += __shfl_xor(s, sft);
                s2 += __shfl_xor(s2, sft);
            }
            if (lane == 0) {
                ws[WS_QNORM + r] = sqrtf(s);
                ws[WS_CNORM + r] = sqrtf(s2);
            }
        }
#pragma unroll
        for (int sft = 32; sft >= 1; sft >>= 1) ssq += __shfl_xor(ssq, sft);
        if (lane == 0) sh[wavein] = ssq;
        __syncthreads();
        if (tid == 0)
            ws[WS_SSQ + blk] = sh[0] + sh[1] + sh[2] + sh[3];

        if (blk == 0) {
            if (tid == 0) { sA = 0; sB = 0; }
            __syncthreads();
            int a = 0, bb = 0;
            for (int i = tid; i < (B_ * T_) / 4; i += 256) {
                const unsigned int w = maskw[i];
                a  |= (w > 1u) ? 1 : 0;
                bb |= (w != 0u && w != 0x3F800000u) ? 1 : 0;
            }
            if (a)  atomicOr(&sA, 1);
            if (bb) atomicOr(&sB, 1);
            __syncthreads();
            if (tid == 0)
                ((int*)ws)[WS_FLAG] = (!sA) ? 0 : ((!sB) ? 1 : 2);
        }
    } else {
        // ---------------- codebook diversity path ----------------
        for (int i = tid; i < G_ * V_; i += 256) sh[i] = 0.0f;
        __syncthreads();
        const int cblk = blk - NORM_BLOCKS;       // 0..255
        const int base = cblk * 4 + wavein;       // 0..1023
        float r0[5] = {0, 0, 0, 0, 0};
        float r1[5] = {0, 0, 0, 0, 0};
        const bool odd = (base & 1);
#pragma unroll 1
        for (int i = 0; i < 16; i++) {
            const int r = base + 1024 * i;        // parity constant per wave
            const float* row = cb + (size_t)r * V_;
            float v[5];
#pragma unroll
            for (int j = 0; j < 5; j++)
                v[j] = __builtin_nontemporal_load(&row[lane + 64 * j]);
            float mx = fmaxf(fmaxf(fmaxf(v[0], v[1]), fmaxf(v[2], v[3])), v[4]);
#pragma unroll
            for (int s = 32; s >= 1; s >>= 1) mx = fmaxf(mx, __shfl_xor(mx, s));
            float e[5], sum = 0.0f;
#pragma unroll
            for (int j = 0; j < 5; j++) { e[j] = __expf(v[j] - mx); sum += e[j]; }
#pragma unroll
            for (int s = 32; s >= 1; s >>= 1) sum += __shfl_xor(sum, s);
            const float is = 1.0f / sum;
            if (odd) {
#pragma unroll
                for (int j = 0; j < 5; j++) r1[j] += e[j] * is;
            } else {
#pragma unroll
                for (int j = 0; j < 5; j++) r0[j] += e[j] * is;
            }
        }
#pragma unroll
        for (int j = 0; j < 5; j++) {
            atomicAdd(&sh[0 * V_ + lane + 64 * j], r0[j]);
            atomicAdd(&sh[1 * V_ + lane + 64 * j], r1[j]);
        }
        __syncthreads();
        for (int i = tid; i < G_ * V_; i += 256)
            atomicAdd(&ws[WS_AVG + i], sh[i]);
    }
}

// ---------------------------------------------------------------------------
// Contrastive: one block per (b,t), b = blk&7 XCD affinity. Indices + norms
// prefetched to LDS; 64 groups of 4 lanes, <=2 targets each; bf16 row
// gathers. Result goes to a DISTINCT per-block slot (plain store) -- the
// single-address atomicAdd serial chain is removed.
// ---------------------------------------------------------------------------
template <bool USE_BF16>
__global__ __launch_bounds__(256) void contrastive_kernel(
    const float* __restrict__ quant,
    const float* __restrict__ ctx,
    const int* __restrict__ negidx,
    const void* __restrict__ maskp,
    float* __restrict__ ws)
{
    const int cblk = blockIdx.x;
    const int b = cblk & 7;                  // batch -> XCD affinity
    const int t = cblk >> 3;
    const int bt = b * T_ + t;

    const int tid = threadIdx.x;
    const int flag = ((const int*)ws)[WS_FLAG];
    bool m;
    if (flag == 2)      m = ((const unsigned char*)maskp)[bt] != 0;
    else if (flag == 1) m = ((const float*)maskp)[bt] != 0.0f;
    else                m = ((const int*)maskp)[bt] != 0;
    if (!m) {                                // block-uniform
        if (tid == 0) ws[WS_LOSSP + cblk] = 0.0f;
        return;
    }

    __shared__ float s_pred[D_];             // 1 KB
    __shared__ int   s_idx[NT_ + 3];
    __shared__ float s_tn[NT_ + 3];          // tn, or -1 for collision
    __shared__ float s_logit[NT_ + 3];

    if (tid < 64)
        ((float4*)s_pred)[tid] = ((const float4*)(ctx + (size_t)bt * D_))[tid];
    if (tid < K_)
        s_idx[tid + 1] = negidx[(size_t)bt * K_ + tid];
    if (tid == K_)
        s_idx[0] = t;
    __syncthreads();
    if (tid < NT_) {
        const int idx = s_idx[tid];
        const bool col = (tid > 0) && (idx == t);
        s_tn[tid] = col ? -1.0f : ws[WS_QNORM + b * T_ + idx];
    }
    __syncthreads();

    const float pn = ws[WS_CNORM + bt];
    const int g = tid >> 2;                  // 0..63
    const int p = tid & 3;

#pragma unroll
    for (int pass = 0; pass < 2; ++pass) {
        const int k = g + 64 * pass;
        if (k < NT_) {
            const int idx = s_idx[k];
            float dot = 0.0f;
            if (USE_BF16) {
                const uint4* row = (const uint4*)((const char*)ws +
                    (size_t)WS_QBF16 * 4 + (size_t)(b * T_ + idx) * 512);
                uint4 u[8];
#pragma unroll
                for (int i = 0; i < 8; ++i) u[i] = row[i * 4 + p];
#pragma unroll
                for (int i = 0; i < 8; ++i) {
                    const int J0 = (p + 4 * i) * 4;   // uint index in row
                    const unsigned int w0 = u[i].x, w1 = u[i].y,
                                       w2 = u[i].z, w3 = u[i].w;
                    const float2 q0 = ((const float2*)s_pred)[J0 + 0];
                    const float2 q1 = ((const float2*)s_pred)[J0 + 1];
                    const float2 q2 = ((const float2*)s_pred)[J0 + 2];
                    const float2 q3 = ((const float2*)s_pred)[J0 + 3];
                    dot += __uint_as_float(w0 << 16) * q0.x
                         + __uint_as_float(w0 & 0xFFFF0000u) * q0.y
                         + __uint_as_float(w1 << 16) * q1.x
                         + __uint_as_float(w1 & 0xFFFF0000u) * q1.y
                         + __uint_as_float(w2 << 16) * q2.x
                         + __uint_as_float(w2 & 0xFFFF0000u) * q2.y
                         + __uint_as_float(w3 << 16) * q3.x
                         + __uint_as_float(w3 & 0xFFFF0000u) * q3.y;
                }
            } else {
                const float4* row = (const float4*)(quant +
                    ((size_t)b * T_ + idx) * D_);
                float4 r[16];
#pragma unroll
                for (int i = 0; i < 16; ++i) r[i] = row[i * 4 + p];
#pragma unroll
                for (int i = 0; i < 16; ++i) {
                    const float4 q = ((const float4*)s_pred)[i * 4 + p];
                    dot += r[i].x * q.x + r[i].y * q.y
                         + r[i].z * q.z + r[i].w * q.w;
                }
            }
            dot += __shfl_xor(dot, 1);
            dot += __shfl_xor(dot, 2);
            if (p == 0) {
                const float tn = s_tn[k];
                s_logit[k] = (tn < 0.0f) ? -1e30f
                    : (dot / fmaxf(pn * tn, COS_EPS_)) * (1.0f / TEMP_);
            }
        }
    }
    __syncthreads();

    if (tid < 64) {
        const float l0 = s_logit[tid];
        const float l1 = (tid + 64 < NT_) ? s_logit[tid + 64] : -1e30f;
        float mx = fmaxf(l0, l1);
#pragma unroll
        for (int s = 32; s >= 1; s >>= 1) mx = fmaxf(mx, __shfl_xor(mx, s));
        float sum = __expf(l0 - mx) + __expf(l1 - mx);
#pragma unroll
        for (int s = 32; s >= 1; s >>= 1) sum += __shfl_xor(sum, s);
        if (tid == 0) {
            const float logp0 = s_logit[0] - (mx + __logf(sum));
            ws[WS_LOSSP + cblk] = -logp0;    // plain store, no contention
        }
    }
}

// ---------------------------------------------------------------------------
// Finalize (256 thr): sum 8192 loss partials; entropy/perplexity; combine.
// ---------------------------------------------------------------------------
__global__ __launch_bounds__(256) void finalize_kernel(
    const float* __restrict__ ws, float* __restrict__ out)
{
    __shared__ float sred[4];
    const int tid = threadIdx.x;
    const int lane = tid & 63;
    const int wavein = tid >> 6;

    float lc = 0.0f;
    for (int i = tid; i < B_ * T_; i += 256) lc += ws[WS_LOSSP + i];
#pragma unroll
    for (int s = 32; s >= 1; s >>= 1) lc += __shfl_xor(lc, s);
    if (lane == 0) sred[wavein] = lc;
    __syncthreads();

    if (tid < 64) {
        float ss = 0.0f;
#pragma unroll
        for (int i = 0; i < 4; i++) ss += ws[WS_SSQ + lane + 64 * i];
        const float* avg = ws + WS_AVG;
        float e0 = 0.0f, e1 = 0.0f;
        const float inv = 1.0f / (float)(B_ * T_);
#pragma unroll
        for (int i = 0; i < 5; i++) {
            const float a0 = avg[0 * V_ + lane + 64 * i] * inv;
            const float a1 = avg[1 * V_ + lane + 64 * i] * inv;
            e0 -= a0 * __logf(a0 + DIV_EPS_);
            e1 -= a1 * __logf(a1 + DIV_EPS_);
        }
#pragma unroll
        for (int s = 32; s >= 1; s >>= 1) {
            ss += __shfl_xor(ss, s);
            e0 += __shfl_xor(e0, s);
            e1 += __shfl_xor(e1, s);
        }
        if (tid == 0) {
            const float loss_c = sred[0] + sred[1] + sred[2] + sred[3];
            const float loss_d = ((float)V_ - __expf(e0)) + ((float)V_ - __expf(e1));
            const float loss_l2 = ss / (float)(B_ * T_ * D_);
            out[0] = loss_c + DIV_W_ * loss_d + L2_W_ * loss_l2;
        }
    }
}

extern "C" void kernel_launch(void* const* d_in, const int* in_sizes, int n_in,
                              void* d_out, int out_size, void* d_ws, size_t ws_size,
                              hipStream_t stream) {
    const float* quant = (const float*)d_in[0];
    const float* ctx   = (const float*)d_in[1];
    const float* cb    = (const float*)d_in[2];
    const int*   nidx  = (const int*)d_in[3];
    const void*  mask  = d_in[4];
    float* ws  = (float*)d_ws;
    float* out = (float*)d_out;

    const bool bf16 = (ws_size >= WS_BF16_BYTES);

    // zero loss_c + avg accumulators (+flag slot)
    hipMemsetAsync(d_ws, 0, (WS_SSQ) * sizeof(float), stream);

    if (bf16) {
        prep_kernel<true><<<NORM_BLOCKS + CB_BLOCKS, 256, 0, stream>>>(
            quant, ctx, cb, (const unsigned int*)mask, ws);
        contrastive_kernel<true><<<B_ * T_, 256, 0, stream>>>(
            quant, ctx, nidx, mask, ws);
    } else {
        prep_kernel<false><<<NORM_BLOCKS + CB_BLOCKS, 256, 0, stream>>>(
            quant, ctx, cb, (const unsigned int*)mask, ws);
        contrastive_kernel<false><<<B_ * T_, 256, 0, stream>>>(
            quant, ctx, nidx, mask, ws);
    }
    finalize_kernel<<<1, 256, 0, stream>>>(ws, out);
}